// Round 3
// baseline (1184.819 us; speedup 1.0000x reference)
//
#include <hip/hip_runtime.h>
#include <math.h>

typedef unsigned short u16;
typedef __attribute__((ext_vector_type(8))) short bf16x8;
typedef __attribute__((ext_vector_type(4))) float f32x4;
typedef __attribute__((ext_vector_type(4))) unsigned short u16x4;

#define NLAYERS 5
#define BATCH 8
#define SEQ 2048
#define CH 512
#define ROWS_TOTAL (BATCH * SEQ)   // 16384
#define HALF (SEQ / 2)             // 1024
#define ATTN_SCALE 0.04419417382415922f  // 512^-0.5

// 128-sq core (qkv/pv/fc1/fc2): double-buffered staging 64 KB -> 2 blocks/CU.
#define SMEM_U16 32768
// qk_res: Q-resident 128 KB + K double-buffer 32 KB = 160 KB (HW max).
#define QRES_U16 65536
#define KBUF_U16 8192

__device__ __forceinline__ u16 f2bf(float f) {
    unsigned u = __float_as_uint(f);
    u += 0x7fffu + ((u >> 16) & 1u);   // RNE
    return (u16)(u >> 16);
}

__device__ __forceinline__ u16x4 pack4(f32x4 v) {
    u16x4 o;
    o.x = f2bf(v[0]); o.y = f2bf(v[1]); o.z = f2bf(v[2]); o.w = f2bf(v[3]);
    return o;
}

__device__ __forceinline__ void st16(u16* p, u16x4 v) { *(u16x4*)p = v; }
__device__ __forceinline__ void st16f(float* p, f32x4 v) { *(f32x4*)p = v; }

// 16-byte async global->LDS DMA. LDS dest = wave-uniform base + lane*16.
__device__ __forceinline__ void llds16(const u16* g, u16* l) {
    __builtin_amdgcn_global_load_lds(
        (const __attribute__((address_space(1))) unsigned int*)g,
        (__attribute__((address_space(3))) unsigned int*)l, 16, 0, 0);
}

// XCD-aware decode for M=16384 row-panel GEMMs (qkv/fc1/fc2): XCD k
// (bid&7) owns row-tiles [16k,16k+16) for all col-tiles -> per-XCD L2
// working set = A-panel 2.1 MB + W <= 1.6 MB < 4 MB.
__device__ __forceinline__ void xcd_rc(int& rt, int& ct) {
    const int n = blockIdx.x;
    const int m = n >> 3;
    rt = (n & 7) * 16 + (m & 15);
    ct = m >> 4;
}

// ---------------------------------------------------------------------------
// Core bf16 MFMA GEMM tile: 128x128 C-tile, 256 threads (4 waves, 2x2 of
// 64x64), 16x16x32 MFMA, BK=64 (32 MFMAs per wave per K-step). A[m][k]
// row-major (lda), Bt[n][k] row-major (ldb). LDS unpadded [128][64] u16 per
// matrix; chunk position p holds global chunk p^(row&7) (0 bank conflicts
// measured). 2-deep double buffer, raw s_barrier + counted s_waitcnt
// vmcnt(8): next tile's 8 global_load_lds stay in flight across the barrier.
// ---------------------------------------------------------------------------
__device__ __forceinline__ void mm_issue(const u16* gA, const u16* gB,
                                         u16* lA, u16* lB, int lda, int ldb)
{
#pragma unroll
    for (int i = 0; i < 4; ++i)    // A: 4 issues x (4 waves x 8 rows)
        llds16(gA + (size_t)i * 32 * lda, lA + i * 2048);
#pragma unroll
    for (int i = 0; i < 4; ++i)
        llds16(gB + (size_t)i * 32 * ldb, lB + i * 2048);
}

__device__ __forceinline__ void mm_compute(const u16* As, const u16* Bs,
                                           const int aoff[2][4],
                                           const int boff[2][4],
                                           f32x4 acc[4][4])
{
#pragma unroll
    for (int h = 0; h < 2; ++h) {
        bf16x8 af[4], bfv[4];
#pragma unroll
        for (int t = 0; t < 4; ++t) af[t]  = *(const bf16x8*)&As[aoff[h][t]];
#pragma unroll
        for (int t = 0; t < 4; ++t) bfv[t] = *(const bf16x8*)&Bs[boff[h][t]];
#pragma unroll
        for (int ti = 0; ti < 4; ++ti)
#pragma unroll
            for (int tj = 0; tj < 4; ++tj)
                acc[ti][tj] = __builtin_amdgcn_mfma_f32_16x16x32_bf16(
                    af[ti], bfv[tj], acc[ti][tj], 0, 0, 0);
    }
}

__device__ __forceinline__ void mm_core(
    const u16* __restrict__ A, int lda,
    const u16* __restrict__ Bt, int ldb,
    int row0, int col0, int K,
    u16* SM, f32x4 acc[4][4])
{
    const int tid  = threadIdx.x;
    const int wave = tid >> 6, lane = tid & 63;
    const int wm = (wave & 1) * 64, wn = (wave >> 1) * 64;
    const int q  = lane >> 4,  ln = lane & 15;

    const int sr8 = lane >> 3;
    const int sc  = (lane & 7) ^ sr8;
    const u16* gA = A  + (size_t)(row0 + wave * 8 + sr8) * lda + sc * 8;
    const u16* gB = Bt + (size_t)(col0 + wave * 8 + sr8) * ldb + sc * 8;

    u16* const A0 = SM;
    u16* const B0 = SM + 8192;
    u16* const A1 = SM + 16384;
    u16* const B1 = SM + 24576;
    u16* const w0a = A0 + wave * 512;
    u16* const w0b = B0 + wave * 512;
    u16* const w1a = A1 + wave * 512;
    u16* const w1b = B1 + wave * 512;

    int aoff[2][4], boff[2][4];
#pragma unroll
    for (int h = 0; h < 2; ++h) {
        const int pos = (((h * 4 + q) ^ (ln & 7)) * 8);
#pragma unroll
        for (int t = 0; t < 4; ++t) {
            aoff[h][t] = (wm + t * 16 + ln) * 64 + pos;
            boff[h][t] = (wn + t * 16 + ln) * 64 + pos;
        }
    }

#pragma unroll
    for (int ti = 0; ti < 4; ++ti)
#pragma unroll
        for (int tj = 0; tj < 4; ++tj)
#pragma unroll
            for (int e = 0; e < 4; ++e) acc[ti][tj][e] = 0.f;

    mm_issue(gA, gB, w0a, w0b, lda, ldb);
    gA += 64; gB += 64;

    for (int k0 = 0; k0 < K; k0 += 128) {
        if (k0 + 64 < K) {
            mm_issue(gA, gB, w1a, w1b, lda, ldb);
            gA += 64; gB += 64;
            asm volatile("s_waitcnt vmcnt(8)" ::: "memory");
        } else {
            asm volatile("s_waitcnt vmcnt(0)" ::: "memory");
        }
        __builtin_amdgcn_s_barrier();
        mm_compute(A0, B0, aoff, boff, acc);
        __builtin_amdgcn_s_barrier();
        __builtin_amdgcn_sched_barrier(0);
        if (k0 + 128 < K) {
            mm_issue(gA, gB, w0a, w0b, lda, ldb);
            gA += 64; gB += 64;
            asm volatile("s_waitcnt vmcnt(8)" ::: "memory");
        } else {
            asm volatile("s_waitcnt vmcnt(0)" ::: "memory");
        }
        __builtin_amdgcn_s_barrier();
        mm_compute(A1, B1, aoff, boff, acc);
        __builtin_amdgcn_s_barrier();
        __builtin_amdgcn_sched_barrier(0);
    }
}

// ---------------------------------------------------------------------------
// Epilogue transpose: round-trip acc through LDS so each thread owns a
// contiguous float4 of one row -> vectorized global I/O. FOUR passes of 32
// rows (eb = 32 x 132 fp32 = 16.9 KB; stride 132 == 4 mod 32 -> conflict-free
// (round-2's 264 == 8 mod 32 was a 4-way conflict)).
// emit(local_row 0..127, col multiple of 4, f32x4).
// ---------------------------------------------------------------------------
template <typename F>
__device__ __forceinline__ void epi_emit(f32x4 acc[4][4], float* eb, F emit)
{
    const int tid = threadIdx.x, wave = tid >> 6, lane = tid & 63;
    const int wn = (wave >> 1) * 64;
    const int q = lane >> 4, ln = lane & 15;
#pragma unroll
    for (int p = 0; p < 4; ++p) {
        __syncthreads();
        if ((wave & 1) == (p >> 1)) {
            const int tibase = (p & 1) * 2;
#pragma unroll
            for (int tj = 0; tj < 4; ++tj)
#pragma unroll
                for (int t2 = 0; t2 < 2; ++t2)
#pragma unroll
                    for (int r = 0; r < 4; ++r)
                        eb[(t2 * 16 + q * 4 + r) * 132 + wn + tj * 16 + ln] =
                            acc[tibase + t2][tj][r];
        }
        __syncthreads();
#pragma unroll
        for (int s = 0; s < 4; ++s) {
            const int row = s * 8 + (tid >> 5);        // 0..31
            const int col = (tid & 31) * 4;
            f32x4 v = *(const f32x4*)&eb[row * 132 + col];
            emit(p * 32 + row, col, v);
        }
    }
}

// ---------------------------------------------------------------------------
// QKV GEMM: A=xb[16384][512], Bt=qkv_wt[1536][512]. 1-D grid (128*12),
// row-panel XCD swizzle. Q (pre-scaled) and K use the vectorized epi; V
// region (ct>=8) keeps the direct acc path (transposed store Vt[b][c][j]).
// ---------------------------------------------------------------------------
__global__ __launch_bounds__(256) void qkv_gemm(
    const u16* __restrict__ A, const u16* __restrict__ Bt,
    const float* __restrict__ bias,
    u16* __restrict__ Qb, u16* __restrict__ Kb, u16* __restrict__ Vt)
{
    __shared__ __align__(16) u16 SMEM[SMEM_U16];
    f32x4 acc[4][4];
    int rt, ct; xcd_rc(rt, ct);
    const int row0 = rt * 128, col0 = ct * 128;
    mm_core(A, CH, Bt, CH, row0, col0, CH, SMEM, acc);

    if (ct < 8) {   // Q or K region (block-uniform)
        u16* dst = (ct < 4) ? Qb : Kb;
        const int cbase = (ct < 4) ? col0 : col0 - CH;
        const float sc = (ct < 4) ? ATTN_SCALE : 1.0f;
        epi_emit(acc, (float*)SMEM, [&](int row, int col, f32x4 v) {
            const float4 bb = *(const float4*)&bias[col0 + col];
            v[0] = (v[0] + bb.x) * sc; v[1] = (v[1] + bb.y) * sc;
            v[2] = (v[2] + bb.z) * sc; v[3] = (v[3] + bb.w) * sc;
            st16(&dst[(size_t)(row0 + row) * CH + cbase + col], pack4(v));
        });
    } else {                // V region: direct path, transposed store
        const int tid = threadIdx.x, wave = tid >> 6, lane = tid & 63;
        const int wm = (wave & 1) * 64, wn = (wave >> 1) * 64;
        const int q = lane >> 4, ln = lane & 15;
#pragma unroll
        for (int tj = 0; tj < 4; ++tj) {
            const int gcol = col0 + wn + tj * 16 + ln;
            const float bv = bias[gcol];
#pragma unroll
            for (int ti = 0; ti < 4; ++ti) {
                const int grow = row0 + wm + ti * 16 + q * 4;
                const int b = grow >> 11, j = grow & (SEQ - 1);
                u16x4 o;
                o.x = f2bf(acc[ti][tj][0] + bv);
                o.y = f2bf(acc[ti][tj][1] + bv);
                o.z = f2bf(acc[ti][tj][2] + bv);
                o.w = f2bf(acc[ti][tj][3] + bv);
                st16(&Vt[(size_t)b * CH * SEQ +
                         (size_t)(gcol - 2 * CH) * SEQ + j], o);
            }
        }
    }
}

// ---------------------------------------------------------------------------
// QK^T, Q-RESIDENT multi-tile version. Grid 256 (1 block/CU, one round):
// b=bid&7 -> XCD=batch (Q 2MB + K 2MB = the XCD's 4MB L2). Block owns a
// contiguous range of 5-6 (it,jt) units out of 164/batch, flattened it-major
// -> <=2 Q restages per block. LDS = Qres 128x512 bf16 (128KB, same
// slot-XOR image as 8 concatenated staged A-tiles) + K double-buffer
// 2x16KB = 160KB. Per unit: 8 BK-64 steps staging ONLY K (counted vmcnt(4)),
// A-frags read from resident Q; then the round-1 epilogue (exp, pack,
// rowsum atomics), eb aliasing the K buffers.
// ---------------------------------------------------------------------------
__global__ __launch_bounds__(256) void qk_res(
    const u16* __restrict__ Qb, const u16* __restrict__ Kb,
    u16* __restrict__ Sb, float* __restrict__ rowsum)
{
    __shared__ __align__(16) u16 SMEM[QRES_U16 + 2 * KBUF_U16];  // 160 KB
    u16* const Qres = SMEM;
    u16* const K0   = SMEM + QRES_U16;
    u16* const K1   = SMEM + QRES_U16 + KBUF_U16;
    float* const eb = (float*)K0;            // 16.9KB epi scratch in 32KB

    const int bid = blockIdx.x;
    const int b = bid & 7, wi = bid >> 3;    // wi = 0..31
    const int u0 = (wi * 164) >> 5, u1 = ((wi + 1) * 164) >> 5;

    const int tid = threadIdx.x;
    const int wave = tid >> 6, lane = tid & 63;
    const int wm = (wave & 1) * 64, wn = (wave >> 1) * 64;
    const int q = lane >> 4, ln = lane & 15;
    const int sr8 = lane >> 3;
    const int sc = (lane & 7) ^ sr8;
    const int w512 = wave * 512;

    const u16* const Qg = Qb + (size_t)b * SEQ * CH;
    const u16* const Kg = Kb + (size_t)b * SEQ * CH;
    u16* const S = Sb + (size_t)b * SEQ * SEQ;

    int aoff[2][4], boff[2][4];
#pragma unroll
    for (int h = 0; h < 2; ++h) {
        const int pos = (((h * 4 + q) ^ (ln & 7)) * 8);
#pragma unroll
        for (int t = 0; t < 4; ++t) {
            aoff[h][t] = (wm + t * 16 + ln) * 64 + pos;
            boff[h][t] = (wn + t * 16 + ln) * 64 + pos;
        }
    }

    int cur_it = -1;
    for (int u = u0; u < u1; ++u) {
        int it, jt;
        if (u < 64) { it = u >> 3; jt = u & 7; }
        else {
            int v = u - 64; it = 8; int len = 9;
            while (v >= len) { v -= len; ++len; ++it; }
            jt = v;
        }

        // ---- stage Q tile (only when it changes): 32 llds16 per wave ----
        if (it != cur_it) {
            cur_it = it;
            const u16* gq = Qg + (size_t)(it * 128 + wave * 8 + sr8) * CH
                               + sc * 8;
#pragma unroll
            for (int kb = 0; kb < 8; ++kb)
#pragma unroll
                for (int i = 0; i < 4; ++i)
                    llds16(gq + (size_t)(i * 32) * CH + kb * 64,
                           Qres + kb * 8192 + i * 2048 + w512);
        }
        // ---- first K tile of this unit -> K0 ----
        const u16* gk = Kg + (size_t)(jt * 128 + wave * 8 + sr8) * CH + sc * 8;
#pragma unroll
        for (int i = 0; i < 4; ++i)
            llds16(gk + (size_t)(i * 32) * CH, K0 + i * 2048 + w512);

        f32x4 acc[4][4];
#pragma unroll
        for (int ti = 0; ti < 4; ++ti)
#pragma unroll
            for (int tj = 0; tj < 4; ++tj)
#pragma unroll
                for (int e = 0; e < 4; ++e) acc[ti][tj][e] = 0.f;

        // ---- 8 BK-64 steps; K double-buffered with counted vmcnt(4).
        // At step s: issue B(s+1) into the buffer holding B(s-1) (its reads
        // finished at step s-1's end barrier), then wait for B(s) (leave
        // B(s+1) in flight), barrier, compute from Qres[kb=s] + KDB[s&1].
#pragma unroll
        for (int s = 0; s < 8; ++s) {
            u16* const nbuf = (s & 1) ? K0 : K1;
            if (s < 7) {
#pragma unroll
                for (int i = 0; i < 4; ++i)
                    llds16(gk + (size_t)(i * 32) * CH + (s + 1) * 64,
                           nbuf + i * 2048 + w512);
                asm volatile("s_waitcnt vmcnt(4)" ::: "memory");
            } else {
                asm volatile("s_waitcnt vmcnt(0)" ::: "memory");
            }
            __builtin_amdgcn_s_barrier();
            mm_compute(Qres + s * 8192, (s & 1) ? K1 : K0, aoff, boff, acc);
            __builtin_amdgcn_s_barrier();
            __builtin_amdgcn_sched_barrier(0);
        }

        // ---- epilogue: exp + pack + store + rowsum (eb aliases K0/K1) ----
        const bool upper = (it < 8);
        const int row0 = it * 128, col0 = jt * 128;
        epi_emit(acc, eb, [&](int row, int col, f32x4 v) {
            const int grow = row0 + row;
            const int gcol = col0 + col;
            f32x4 pv;
#pragma unroll
            for (int e = 0; e < 4; ++e) {
                const bool allowed = upper || (gcol + e <= grow);
                pv[e] = allowed ? __expf(fminf(v[e], 60.f)) : 0.f;
            }
            st16(&S[(size_t)grow * SEQ + gcol], pack4(pv));
            float rs = pv[0] + pv[1] + pv[2] + pv[3];
            rs += __shfl_xor(rs, 1, 64);
            rs += __shfl_xor(rs, 2, 64);
            rs += __shfl_xor(rs, 4, 64);
            rs += __shfl_xor(rs, 8, 64);
            rs += __shfl_xor(rs, 16, 64);
            if ((tid & 31) == 0)
                atomicAdd(&rowsum[b * SEQ + grow], rs);
        });
        __syncthreads();   // eb reads done before next unit scribbles K0/K1
    }
}

// ---------------------------------------------------------------------------
// PV GEMM (128-sq), full-K per block, normalized output. Grid 512: b=id&7 ->
// XCD=batch (Vt 2MB L2-resident), heavy row-tiles first. Exactly one round.
// ---------------------------------------------------------------------------
__global__ __launch_bounds__(256) void pv_gemm(
    const u16* __restrict__ Sb, const u16* __restrict__ Vt,
    const float* __restrict__ rowsum, float* __restrict__ O)
{
    const int n = blockIdx.x;
    const int b = n & 7, m = n >> 3;        // m = 0..63
    const int it = 15 - (m >> 2), ct = m & 3;
    const int Kfull = ((it < 8) ? 8 : (it + 1)) * 128;
    __shared__ __align__(16) u16 SMEM[SMEM_U16];
    f32x4 acc[4][4];
    const u16* A  = Sb + (size_t)b * SEQ * SEQ;
    const u16* Bt = Vt + (size_t)b * CH * SEQ;
    const int row0 = it * 128, col0 = ct * 128;
    mm_core(A, SEQ, Bt, SEQ, row0, col0, Kfull, SMEM, acc);

    epi_emit(acc, (float*)SMEM, [&](int row, int col, f32x4 v) {
        const int grow = row0 + row;
        const float rden = 1.0f / rowsum[b * SEQ + grow];
        v[0] *= rden; v[1] *= rden; v[2] *= rden; v[3] *= rden;
        st16f(&O[(size_t)(b * SEQ + grow) * CH + col0 + col], v);
    });
}

// ---------------------------------------------------------------------------
// fc1: bf16 in/out, exact GELU epilogue. Row-panel XCD swizzle.
// ---------------------------------------------------------------------------
__global__ __launch_bounds__(256) void fc1_gemm(
    const u16* __restrict__ A, const u16* __restrict__ Bt,
    const float* __restrict__ bias, u16* __restrict__ H)
{
    __shared__ __align__(16) u16 SMEM[SMEM_U16];
    f32x4 acc[4][4];
    int rt, ct; xcd_rc(rt, ct);
    const int row0 = rt * 128, col0 = ct * 128;
    mm_core(A, CH, Bt, CH, row0, col0, CH, SMEM, acc);
    epi_emit(acc, (float*)SMEM, [&](int row, int col, f32x4 v) {
        const float4 bb = *(const float4*)&bias[col0 + col];
        v[0] += bb.x; v[1] += bb.y; v[2] += bb.z; v[3] += bb.w;
#pragma unroll
        for (int e = 0; e < 4; ++e)
            v[e] = 0.5f * v[e] * (1.f + erff(v[e] * 0.70710678118654752f));
        st16(&H[(size_t)(row0 + row) * (2 * CH) + col0 + col], pack4(v));
    });
}

// ---------------------------------------------------------------------------
// fc2: bf16 in, +bias + fp32 residual (normalized O). Writes bf16 Xb always;
// fp32 X only on the final layer. Row-panel XCD swizzle.
// ---------------------------------------------------------------------------
template <bool WRITE_X>
__global__ __launch_bounds__(256) void fc2_gemm(
    const u16* __restrict__ A, const u16* __restrict__ Bt,
    const float* __restrict__ bias, float* __restrict__ X,
    u16* __restrict__ Xb)
{
    __shared__ __align__(16) u16 SMEM[SMEM_U16];
    f32x4 acc[4][4];
    int rt, ct; xcd_rc(rt, ct);
    const int row0 = rt * 128, col0 = ct * 128;
    mm_core(A, 2 * CH, Bt, 2 * CH, row0, col0, 2 * CH, SMEM, acc);
    epi_emit(acc, (float*)SMEM, [&](int row, int col, f32x4 v) {
        const size_t idx = (size_t)(row0 + row) * CH + col0 + col;
        const float4 bb = *(const float4*)&bias[col0 + col];
        const f32x4 xv = *(const f32x4*)&X[idx];
        v[0] += bb.x + xv[0]; v[1] += bb.y + xv[1];
        v[2] += bb.z + xv[2]; v[3] += bb.w + xv[3];
        if (WRITE_X) st16f(&X[idx], v);
        st16(&Xb[idx], pack4(v));
    });
}

// ---------------------------------------------------------------------------
// LayerNorm: fp32 in (normalized attention out), bf16 out (feeds fc1).
// ---------------------------------------------------------------------------
__device__ __forceinline__ float block_sum(float v, volatile float* red, int tid)
{
#pragma unroll
    for (int off = 1; off < 64; off <<= 1) v += __shfl_xor(v, off, 64);
    __syncthreads();
    if ((tid & 63) == 0) red[tid >> 6] = v;
    __syncthreads();
    return red[0] + red[1] + red[2] + red[3];
}

__global__ __launch_bounds__(256) void ln_kernel(
    const float* __restrict__ x, const float* __restrict__ g,
    const float* __restrict__ bta, u16* __restrict__ y)
{
    __shared__ float red[4];
    const int tid = threadIdx.x;
    const size_t base = (size_t)blockIdx.x * CH;
    float x0 = x[base + tid];
    float x1 = x[base + 256 + tid];
    float mu = block_sum(x0 + x1, red, tid) * (1.f / CH);
    float d0 = x0 - mu, d1 = x1 - mu;
    float var = block_sum(d0 * d0 + d1 * d1, red, tid) * (1.f / CH);
    float w = 1.f / sqrtf(var + 1e-5f);
    y[base + tid]       = f2bf(d0 * w * g[tid]       + bta[tid]);
    y[base + 256 + tid] = f2bf(d1 * w * g[256 + tid] + bta[256 + tid]);
}

// ---------------------------------------------------------------------------
// fp32 -> bf16 elementwise (4/thread).
// ---------------------------------------------------------------------------
__global__ __launch_bounds__(256) void f2bf_kernel(
    const float* __restrict__ in, u16* __restrict__ out)
{
    const int i = blockIdx.x * 256 + threadIdx.x;
    float4 v = ((const float4*)in)[i];
    ushort4 o;
    o.x = f2bf(v.x); o.y = f2bf(v.y); o.z = f2bf(v.z); o.w = f2bf(v.w);
    ((ushort4*)out)[i] = o;
}

// ---------------------------------------------------------------------------
// Weight transpose-convert: in fp32 [L][K][N] -> out bf16 [L][N][K].
// ---------------------------------------------------------------------------
__global__ __launch_bounds__(256) void wtrans_kernel(
    const float* __restrict__ in, u16* __restrict__ out, int K, int N)
{
    __shared__ float tile[32][33];
    const int l = blockIdx.z;
    in  += (size_t)l * K * N;
    out += (size_t)l * K * N;
    const int n0 = blockIdx.x * 32, k0 = blockIdx.y * 32;
    const int r = threadIdx.x >> 3, c4 = (threadIdx.x & 7) * 4;
    float4 v = *(const float4*)&in[(size_t)(k0 + r) * N + n0 + c4];
    tile[r][c4 + 0] = v.x; tile[r][c4 + 1] = v.y;
    tile[r][c4 + 2] = v.z; tile[r][c4 + 3] = v.w;
    __syncthreads();
    ushort4 o;
    o.x = f2bf(tile[c4 + 0][r]); o.y = f2bf(tile[c4 + 1][r]);
    o.z = f2bf(tile[c4 + 2][r]); o.w = f2bf(tile[c4 + 3][r]);
    *(ushort4*)&out[(size_t)(n0 + r) * K + k0 + c4] = o;
}

// ---------------------------------------------------------------------------
extern "C" void kernel_launch(void* const* d_in, const int* in_sizes, int n_in,
                              void* d_out, int out_size, void* d_ws, size_t ws_size,
                              hipStream_t stream)
{
    const float* x_in  = (const float*)d_in[0];
    const float* qkv_w = (const float*)d_in[1];
    const float* qkv_b = (const float*)d_in[2];
    const float* ln_g  = (const float*)d_in[3];
    const float* ln_b  = (const float*)d_in[4];
    const float* fc1_w = (const float*)d_in[5];
    const float* fc1_b = (const float*)d_in[6];
    const float* fc2_w = (const float*)d_in[7];
    const float* fc2_b = (const float*)d_in[8];

    float* xbuf = (float*)d_out;   // fp32 working x (B,N,C) — also final out

    // Workspace carve (bytes). Total ≈ 152.7 MB.
    char* p = (char*)d_ws;
    u16* qkv_wt = (u16*)p; p += (size_t)NLAYERS * 1536 * 512 * 2;
    u16* fc1_wt = (u16*)p; p += (size_t)NLAYERS * 1024 * 512 * 2;
    u16* fc2_wt = (u16*)p; p += (size_t)NLAYERS * 512 * 1024 * 2;
    u16* xb = (u16*)p; p += (size_t)ROWS_TOTAL * CH * 2;
    u16* Qb = (u16*)p; p += (size_t)ROWS_TOTAL * CH * 2;
    u16* Kb = (u16*)p; p += (size_t)ROWS_TOTAL * CH * 2;
    u16* Vt = (u16*)p; p += (size_t)ROWS_TOTAL * CH * 2;
    float* rowsum = (float*)p; p += (size_t)ROWS_TOTAL * 4;
    u16* Sb = (u16*)p;                       // attention phase
    u16* yb = Sb;                            // alias: LN out (MLP phase)
    u16* hb = Sb + (size_t)ROWS_TOTAL * CH;  // alias: GELU out (MLP phase)

    const dim3 blk(256);

    f2bf_kernel<<<dim3(ROWS_TOTAL * CH / 1024), blk, 0, stream>>>(x_in, xb);
    wtrans_kernel<<<dim3(1536 / 32, 512 / 32, NLAYERS), blk, 0, stream>>>(
        qkv_w, qkv_wt, 512, 1536);
    wtrans_kernel<<<dim3(1024 / 32, 512 / 32, NLAYERS), blk, 0, stream>>>(
        fc1_w, fc1_wt, 512, 1024);
    wtrans_kernel<<<dim3(512 / 32, 1024 / 32, NLAYERS), blk, 0, stream>>>(
        fc2_w, fc2_wt, 1024, 512);

    for (int l = 0; l < NLAYERS; ++l) {
        qkv_gemm<<<dim3(128 * 12), blk, 0, stream>>>(
            xb, qkv_wt + (size_t)l * 1536 * 512, qkv_b + (size_t)l * 1536,
            Qb, Kb, Vt);
        hipMemsetAsync(rowsum, 0, (size_t)ROWS_TOTAL * 4, stream);
        qk_res<<<dim3(256), blk, 0, stream>>>(Qb, Kb, Sb, rowsum);
        pv_gemm<<<dim3(512), blk, 0, stream>>>(Sb, Vt, rowsum, xbuf);
        ln_kernel<<<dim3(ROWS_TOTAL), blk, 0, stream>>>(
            xbuf, ln_g + (size_t)l * CH, ln_b + (size_t)l * CH, yb);
        fc1_gemm<<<dim3(128 * 8), blk, 0, stream>>>(
            yb, fc1_wt + (size_t)l * 1024 * 512, fc1_b + (size_t)l * 1024, hb);
        if (l < NLAYERS - 1)
            fc2_gemm<false><<<dim3(128 * 4), blk, 0, stream>>>(
                hb, fc2_wt + (size_t)l * 512 * 1024, fc2_b + (size_t)l * 512,
                xbuf, xb);
        else
            fc2_gemm<true><<<dim3(128 * 4), blk, 0, stream>>>(
                hb, fc2_wt + (size_t)l * 512 * 1024, fc2_b + (size_t)l * 512,
                xbuf, xb);
    }
}

// Round 4
// 1044.818 us; speedup vs baseline: 1.1340x; 1.1340x over previous
//
#include <hip/hip_runtime.h>
#include <math.h>

typedef unsigned short u16;
typedef __attribute__((ext_vector_type(8))) short bf16x8;
typedef __attribute__((ext_vector_type(4))) float f32x4;
typedef __attribute__((ext_vector_type(4))) unsigned short u16x4;

#define NLAYERS 5
#define BATCH 8
#define SEQ 2048
#define CH 512
#define ROWS_TOTAL (BATCH * SEQ)   // 16384
#define HALF (SEQ / 2)             // 1024
// Q prescale folds softmax scale AND log2(e): qk's epilogue is then a bare
// v_exp_f32 (exp2). 512^-0.5 * 1.4426950408889634 :
#define QSCALE_EXP2 0.06375871529f
// exp cap in exp2 domain (= old 60.0 in e-domain).
#define EXP2_CAP 86.56f

// Double-buffered mm_core staging {As0,Bs0,As1,Bs1} x 16 KB = 64 KB
// -> 2 blocks/CU. Epilogue transpose buffer (32 x 132 fp32) aliases buf0.
#define SMEM_U16 32768

// Packed bf16 convert: v_cvt_pk_bf16_f32 (RNE) replaces 3 bit-ops/elem.
__device__ __forceinline__ u16 f2bf(float f) {
    unsigned u = __float_as_uint(f);
    u += 0x7fffu + ((u >> 16) & 1u);   // RNE (scalar fallback)
    return (u16)(u >> 16);
}

__device__ __forceinline__ unsigned pk2(float a, float b) {
    unsigned r;
    asm("v_cvt_pk_bf16_f32 %0, %1, %2" : "=v"(r) : "v"(a), "v"(b));
    return r;
}

__device__ __forceinline__ u16x4 pack4(f32x4 v) {
    union { unsigned u[2]; u16x4 o; } r;
    r.u[0] = pk2(v[0], v[1]);
    r.u[1] = pk2(v[2], v[3]);
    return r.o;
}

__device__ __forceinline__ void st16(u16* p, u16x4 v) { *(u16x4*)p = v; }
__device__ __forceinline__ void st16f(float* p, f32x4 v) { *(f32x4*)p = v; }

__device__ __forceinline__ float fexp2(float x) {
    float r;
    asm("v_exp_f32 %0, %1" : "=v"(r) : "v"(x));
    return r;
}

// 16-byte async global->LDS DMA. LDS dest = wave-uniform base + lane*16.
__device__ __forceinline__ void llds16(const u16* g, u16* l) {
    __builtin_amdgcn_global_load_lds(
        (const __attribute__((address_space(1))) unsigned int*)g,
        (__attribute__((address_space(3))) unsigned int*)l, 16, 0, 0);
}

// XCD-aware decode for M=16384 row-panel GEMMs (qkv/fc1/fc2): XCD k
// (bid&7) owns row-tiles [16k,16k+16) for all col-tiles -> per-XCD L2
// working set = A-panel 2.1 MB + W <= 1.6 MB < 4 MB.
__device__ __forceinline__ void xcd_rc(int& rt, int& ct) {
    const int n = blockIdx.x;
    const int m = n >> 3;
    rt = (n & 7) * 16 + (m & 15);
    ct = m >> 4;
}

// ---------------------------------------------------------------------------
// Core bf16 MFMA GEMM tile: 128x128 C-tile, 256 threads (4 waves, 2x2 of
// 64x64), 16x16x32 MFMA, BK=64 (32 MFMAs per wave per K-step). A[m][k]
// row-major (lda), Bt[n][k] row-major (ldb). LDS unpadded [128][64] u16 per
// matrix; chunk position p holds global chunk p^(row&7) (0 bank conflicts
// measured). 2-deep double buffer, raw s_barrier + counted s_waitcnt
// vmcnt(8): next tile's 8 global_load_lds stay in flight across the barrier.
// ---------------------------------------------------------------------------
__device__ __forceinline__ void mm_issue(const u16* gA, const u16* gB,
                                         u16* lA, u16* lB, int lda, int ldb)
{
#pragma unroll
    for (int i = 0; i < 4; ++i)    // A: 4 issues x (4 waves x 8 rows)
        llds16(gA + (size_t)i * 32 * lda, lA + i * 2048);
#pragma unroll
    for (int i = 0; i < 4; ++i)
        llds16(gB + (size_t)i * 32 * ldb, lB + i * 2048);
}

__device__ __forceinline__ void mm_compute(const u16* As, const u16* Bs,
                                           const int aoff[2][4],
                                           const int boff[2][4],
                                           f32x4 acc[4][4])
{
#pragma unroll
    for (int h = 0; h < 2; ++h) {
        bf16x8 af[4], bfv[4];
#pragma unroll
        for (int t = 0; t < 4; ++t) af[t]  = *(const bf16x8*)&As[aoff[h][t]];
#pragma unroll
        for (int t = 0; t < 4; ++t) bfv[t] = *(const bf16x8*)&Bs[boff[h][t]];
#pragma unroll
        for (int ti = 0; ti < 4; ++ti)
#pragma unroll
            for (int tj = 0; tj < 4; ++tj)
                acc[ti][tj] = __builtin_amdgcn_mfma_f32_16x16x32_bf16(
                    af[ti], bfv[tj], acc[ti][tj], 0, 0, 0);
    }
}

__device__ __forceinline__ void mm_core(
    const u16* __restrict__ A, int lda,
    const u16* __restrict__ Bt, int ldb,
    int row0, int col0, int K,
    u16* SM, f32x4 acc[4][4])
{
    const int tid  = threadIdx.x;
    const int wave = tid >> 6, lane = tid & 63;
    const int wm = (wave & 1) * 64, wn = (wave >> 1) * 64;
    const int q  = lane >> 4,  ln = lane & 15;

    const int sr8 = lane >> 3;
    const int sc  = (lane & 7) ^ sr8;
    const u16* gA = A  + (size_t)(row0 + wave * 8 + sr8) * lda + sc * 8;
    const u16* gB = Bt + (size_t)(col0 + wave * 8 + sr8) * ldb + sc * 8;

    u16* const A0 = SM;
    u16* const B0 = SM + 8192;
    u16* const A1 = SM + 16384;
    u16* const B1 = SM + 24576;
    u16* const w0a = A0 + wave * 512;
    u16* const w0b = B0 + wave * 512;
    u16* const w1a = A1 + wave * 512;
    u16* const w1b = B1 + wave * 512;

    int aoff[2][4], boff[2][4];
#pragma unroll
    for (int h = 0; h < 2; ++h) {
        const int pos = (((h * 4 + q) ^ (ln & 7)) * 8);
#pragma unroll
        for (int t = 0; t < 4; ++t) {
            aoff[h][t] = (wm + t * 16 + ln) * 64 + pos;
            boff[h][t] = (wn + t * 16 + ln) * 64 + pos;
        }
    }

#pragma unroll
    for (int ti = 0; ti < 4; ++ti)
#pragma unroll
        for (int tj = 0; tj < 4; ++tj)
#pragma unroll
            for (int e = 0; e < 4; ++e) acc[ti][tj][e] = 0.f;

    mm_issue(gA, gB, w0a, w0b, lda, ldb);
    gA += 64; gB += 64;

    for (int k0 = 0; k0 < K; k0 += 128) {
        if (k0 + 64 < K) {
            mm_issue(gA, gB, w1a, w1b, lda, ldb);
            gA += 64; gB += 64;
            asm volatile("s_waitcnt vmcnt(8)" ::: "memory");
        } else {
            asm volatile("s_waitcnt vmcnt(0)" ::: "memory");
        }
        __builtin_amdgcn_s_barrier();
        mm_compute(A0, B0, aoff, boff, acc);
        __builtin_amdgcn_s_barrier();
        __builtin_amdgcn_sched_barrier(0);
        if (k0 + 128 < K) {
            mm_issue(gA, gB, w0a, w0b, lda, ldb);
            gA += 64; gB += 64;
            asm volatile("s_waitcnt vmcnt(8)" ::: "memory");
        } else {
            asm volatile("s_waitcnt vmcnt(0)" ::: "memory");
        }
        __builtin_amdgcn_s_barrier();
        mm_compute(A1, B1, aoff, boff, acc);
        __builtin_amdgcn_s_barrier();
        __builtin_amdgcn_sched_barrier(0);
    }
}

// ---------------------------------------------------------------------------
// Epilogue transpose: round-trip acc through LDS so each thread owns a
// contiguous float4 of one row -> vectorized global I/O. FOUR passes of 32
// rows (eb = 32 x 132 fp32 = 16.9 KB; stride 132 == 4 mod 32 -> conflict-
// free). emit(local_row 0..127, col multiple of 4, f32x4).
// ---------------------------------------------------------------------------
template <typename F>
__device__ __forceinline__ void epi_emit(f32x4 acc[4][4], float* eb, F emit)
{
    const int tid = threadIdx.x, wave = tid >> 6, lane = tid & 63;
    const int wn = (wave >> 1) * 64;
    const int q = lane >> 4, ln = lane & 15;
#pragma unroll
    for (int p = 0; p < 4; ++p) {
        __syncthreads();
        if ((wave & 1) == (p >> 1)) {
            const int tibase = (p & 1) * 2;
#pragma unroll
            for (int tj = 0; tj < 4; ++tj)
#pragma unroll
                for (int t2 = 0; t2 < 2; ++t2)
#pragma unroll
                    for (int r = 0; r < 4; ++r)
                        eb[(t2 * 16 + q * 4 + r) * 132 + wn + tj * 16 + ln] =
                            acc[tibase + t2][tj][r];
        }
        __syncthreads();
#pragma unroll
        for (int s = 0; s < 4; ++s) {
            const int row = s * 8 + (tid >> 5);        // 0..31
            const int col = (tid & 31) * 4;
            f32x4 v = *(const f32x4*)&eb[row * 132 + col];
            emit(p * 32 + row, col, v);
        }
    }
}

// ---------------------------------------------------------------------------
// QKV GEMM: A=xb[16384][512], Bt=qkv_wt[1536][512]. 1-D grid (128*12),
// row-panel XCD swizzle. Q (pre-scaled by QSCALE_EXP2) and K use the
// vectorized epi; V region (ct>=8) keeps the direct acc path (transposed
// store Vt[b][c][j]). ct==0 blocks also zero rowsum (replaces the memset
// dispatch; safe: previous layer's pv already consumed rowsum).
// ---------------------------------------------------------------------------
__global__ __launch_bounds__(256) void qkv_gemm(
    const u16* __restrict__ A, const u16* __restrict__ Bt,
    const float* __restrict__ bias,
    u16* __restrict__ Qb, u16* __restrict__ Kb, u16* __restrict__ Vt,
    float* __restrict__ rowsum)
{
    __shared__ __align__(16) u16 SMEM[SMEM_U16];
    f32x4 acc[4][4];
    int rt, ct; xcd_rc(rt, ct);
    const int row0 = rt * 128, col0 = ct * 128;
    if (ct == 0 && threadIdx.x < 128)
        rowsum[row0 + threadIdx.x] = 0.f;
    mm_core(A, CH, Bt, CH, row0, col0, CH, SMEM, acc);

    if (ct < 8) {   // Q or K region (block-uniform)
        u16* dst = (ct < 4) ? Qb : Kb;
        const int cbase = (ct < 4) ? col0 : col0 - CH;
        const float sc = (ct < 4) ? QSCALE_EXP2 : 1.0f;
        epi_emit(acc, (float*)SMEM, [&](int row, int col, f32x4 v) {
            const float4 bb = *(const float4*)&bias[col0 + col];
            v[0] = (v[0] + bb.x) * sc; v[1] = (v[1] + bb.y) * sc;
            v[2] = (v[2] + bb.z) * sc; v[3] = (v[3] + bb.w) * sc;
            st16(&dst[(size_t)(row0 + row) * CH + cbase + col], pack4(v));
        });
    } else {                // V region: direct path, transposed store
        const int tid = threadIdx.x, wave = tid >> 6, lane = tid & 63;
        const int wm = (wave & 1) * 64, wn = (wave >> 1) * 64;
        const int q = lane >> 4, ln = lane & 15;
#pragma unroll
        for (int tj = 0; tj < 4; ++tj) {
            const int gcol = col0 + wn + tj * 16 + ln;
            const float bv = bias[gcol];
#pragma unroll
            for (int ti = 0; ti < 4; ++ti) {
                const int grow = row0 + wm + ti * 16 + q * 4;
                const int b = grow >> 11, j = grow & (SEQ - 1);
                f32x4 vv;
                vv[0] = acc[ti][tj][0] + bv; vv[1] = acc[ti][tj][1] + bv;
                vv[2] = acc[ti][tj][2] + bv; vv[3] = acc[ti][tj][3] + bv;
                st16(&Vt[(size_t)b * CH * SEQ +
                         (size_t)(gcol - 2 * CH) * SEQ + j], pack4(vv));
            }
        }
    }
}

// ---------------------------------------------------------------------------
// QK^T GEMM, fused unnormalized softmax (exp2 domain; Q carries the
// log2e*scale factor). 1-D grid 2048: b=id&7 -> XCD=batch (K 2MB resident
// in the owner XCD's L2). jt=(id>>3)&15, it=id>>7; masked tiles early-out.
// Writes P'=exp2(s) bf16 (0 where masked), accumulates rowsum.
// ---------------------------------------------------------------------------
__global__ __launch_bounds__(256) void qk_gemm(
    const u16* __restrict__ Qb, const u16* __restrict__ Kb,
    u16* __restrict__ Sb, float* __restrict__ rowsum)
{
    const int id = blockIdx.x;
    const int b = id & 7, jt = (id >> 3) & 15, it = id >> 7;
    if (it < 8) { if (jt >= 8) return; } else if (jt > it) return;
    __shared__ __align__(16) u16 SMEM[SMEM_U16];
    f32x4 acc[4][4];
    const u16* A  = Qb + (size_t)b * SEQ * CH;
    const u16* Bt = Kb + (size_t)b * SEQ * CH;
    u16* S = Sb + (size_t)b * SEQ * SEQ;
    const int row0 = it * 128, col0 = jt * 128;
    mm_core(A, CH, Bt, CH, row0, col0, CH, SMEM, acc);

    const bool upper = (it < 8);
    const int tid = threadIdx.x;
    epi_emit(acc, (float*)SMEM, [&](int row, int col, f32x4 v) {
        const int grow = row0 + row;        // i within batch
        const int gcol = col0 + col;        // j
        f32x4 pv;
#pragma unroll
        for (int e = 0; e < 4; ++e) {
            const bool allowed = upper || (gcol + e <= grow);
            pv[e] = allowed ? fexp2(fminf(v[e], EXP2_CAP)) : 0.f;
        }
        st16(&S[(size_t)grow * SEQ + gcol], pack4(pv));
        float rs = pv[0] + pv[1] + pv[2] + pv[3];
        rs += __shfl_xor(rs, 1, 64);
        rs += __shfl_xor(rs, 2, 64);
        rs += __shfl_xor(rs, 4, 64);
        rs += __shfl_xor(rs, 8, 64);
        rs += __shfl_xor(rs, 16, 64);
        if ((tid & 31) == 0)
            atomicAdd(&rowsum[b * SEQ + grow], rs);
    });
}

// ---------------------------------------------------------------------------
// PV GEMM, full-K per block, normalized output. 1-D grid 512: b=id&7 ->
// XCD=batch (Vt 2MB L2-resident), heavy row-tiles first. Exactly one round.
// ---------------------------------------------------------------------------
__global__ __launch_bounds__(256) void pv_gemm(
    const u16* __restrict__ Sb, const u16* __restrict__ Vt,
    const float* __restrict__ rowsum, float* __restrict__ O)
{
    const int n = blockIdx.x;
    const int b = n & 7, m = n >> 3;        // m = 0..63
    const int it = 15 - (m >> 2), ct = m & 3;
    const int Kfull = ((it < 8) ? 8 : (it + 1)) * 128;
    __shared__ __align__(16) u16 SMEM[SMEM_U16];
    f32x4 acc[4][4];
    const u16* A  = Sb + (size_t)b * SEQ * SEQ;
    const u16* Bt = Vt + (size_t)b * CH * SEQ;
    const int row0 = it * 128, col0 = ct * 128;
    mm_core(A, SEQ, Bt, SEQ, row0, col0, Kfull, SMEM, acc);

    epi_emit(acc, (float*)SMEM, [&](int row, int col, f32x4 v) {
        const int grow = row0 + row;
        const float rden = 1.0f / rowsum[b * SEQ + grow];
        v[0] *= rden; v[1] *= rden; v[2] *= rden; v[3] *= rden;
        st16f(&O[(size_t)(b * SEQ + grow) * CH + col0 + col], v);
    });
}

// ---------------------------------------------------------------------------
// fc1: bf16 in/out, exact GELU epilogue. Row-panel XCD swizzle.
// ---------------------------------------------------------------------------
__global__ __launch_bounds__(256) void fc1_gemm(
    const u16* __restrict__ A, const u16* __restrict__ Bt,
    const float* __restrict__ bias, u16* __restrict__ H)
{
    __shared__ __align__(16) u16 SMEM[SMEM_U16];
    f32x4 acc[4][4];
    int rt, ct; xcd_rc(rt, ct);
    const int row0 = rt * 128, col0 = ct * 128;
    mm_core(A, CH, Bt, CH, row0, col0, CH, SMEM, acc);
    epi_emit(acc, (float*)SMEM, [&](int row, int col, f32x4 v) {
        const float4 bb = *(const float4*)&bias[col0 + col];
        v[0] += bb.x; v[1] += bb.y; v[2] += bb.z; v[3] += bb.w;
#pragma unroll
        for (int e = 0; e < 4; ++e)
            v[e] = 0.5f * v[e] * (1.f + erff(v[e] * 0.70710678118654752f));
        st16(&H[(size_t)(row0 + row) * (2 * CH) + col0 + col], pack4(v));
    });
}

// ---------------------------------------------------------------------------
// fc2: bf16 in, +bias + fp32 residual (normalized O). Writes bf16 Xb always;
// fp32 X only on the final layer. Row-panel XCD swizzle.
// ---------------------------------------------------------------------------
template <bool WRITE_X>
__global__ __launch_bounds__(256) void fc2_gemm(
    const u16* __restrict__ A, const u16* __restrict__ Bt,
    const float* __restrict__ bias, float* __restrict__ X,
    u16* __restrict__ Xb)
{
    __shared__ __align__(16) u16 SMEM[SMEM_U16];
    f32x4 acc[4][4];
    int rt, ct; xcd_rc(rt, ct);
    const int row0 = rt * 128, col0 = ct * 128;
    mm_core(A, 2 * CH, Bt, 2 * CH, row0, col0, 2 * CH, SMEM, acc);
    epi_emit(acc, (float*)SMEM, [&](int row, int col, f32x4 v) {
        const size_t idx = (size_t)(row0 + row) * CH + col0 + col;
        const float4 bb = *(const float4*)&bias[col0 + col];
        const f32x4 xv = *(const f32x4*)&X[idx];
        v[0] += bb.x + xv[0]; v[1] += bb.y + xv[1];
        v[2] += bb.z + xv[2]; v[3] += bb.w + xv[3];
        if (WRITE_X) st16f(&X[idx], v);
        st16(&Xb[idx], pack4(v));
    });
}

// ---------------------------------------------------------------------------
// LayerNorm: fp32 in (normalized attention out), bf16 out (feeds fc1).
// ---------------------------------------------------------------------------
__device__ __forceinline__ float block_sum(float v, volatile float* red, int tid)
{
#pragma unroll
    for (int off = 1; off < 64; off <<= 1) v += __shfl_xor(v, off, 64);
    __syncthreads();
    if ((tid & 63) == 0) red[tid >> 6] = v;
    __syncthreads();
    return red[0] + red[1] + red[2] + red[3];
}

__global__ __launch_bounds__(256) void ln_kernel(
    const float* __restrict__ x, const float* __restrict__ g,
    const float* __restrict__ bta, u16* __restrict__ y)
{
    __shared__ float red[4];
    const int tid = threadIdx.x;
    const size_t base = (size_t)blockIdx.x * CH;
    float x0 = x[base + tid];
    float x1 = x[base + 256 + tid];
    float mu = block_sum(x0 + x1, red, tid) * (1.f / CH);
    float d0 = x0 - mu, d1 = x1 - mu;
    float var = block_sum(d0 * d0 + d1 * d1, red, tid) * (1.f / CH);
    float w = 1.f / sqrtf(var + 1e-5f);
    const float y0 = d0 * w * g[tid]       + bta[tid];
    const float y1 = d1 * w * g[256 + tid] + bta[256 + tid];
    const unsigned pk = pk2(y0, y1);
    y[base + tid]       = (u16)(pk & 0xffffu);
    y[base + 256 + tid] = (u16)(pk >> 16);
}

// ---------------------------------------------------------------------------
// fp32 -> bf16 elementwise (4/thread).
// ---------------------------------------------------------------------------
__global__ __launch_bounds__(256) void f2bf_kernel(
    const float* __restrict__ in, u16* __restrict__ out)
{
    const int i = blockIdx.x * 256 + threadIdx.x;
    float4 vv = ((const float4*)in)[i];
    f32x4 v; v[0] = vv.x; v[1] = vv.y; v[2] = vv.z; v[3] = vv.w;
    u16x4 o = pack4(v);
    *(u16x4*)&out[(size_t)i * 4] = o;
}

// ---------------------------------------------------------------------------
// Weight transpose-convert: in fp32 [L][K][N] -> out bf16 [L][N][K].
// ---------------------------------------------------------------------------
__global__ __launch_bounds__(256) void wtrans_kernel(
    const float* __restrict__ in, u16* __restrict__ out, int K, int N)
{
    __shared__ float tile[32][33];
    const int l = blockIdx.z;
    in  += (size_t)l * K * N;
    out += (size_t)l * K * N;
    const int n0 = blockIdx.x * 32, k0 = blockIdx.y * 32;
    const int r = threadIdx.x >> 3, c4 = (threadIdx.x & 7) * 4;
    float4 v = *(const float4*)&in[(size_t)(k0 + r) * N + n0 + c4];
    tile[r][c4 + 0] = v.x; tile[r][c4 + 1] = v.y;
    tile[r][c4 + 2] = v.z; tile[r][c4 + 3] = v.w;
    __syncthreads();
    f32x4 t;
    t[0] = tile[c4 + 0][r]; t[1] = tile[c4 + 1][r];
    t[2] = tile[c4 + 2][r]; t[3] = tile[c4 + 3][r];
    st16(&out[(size_t)(n0 + r) * K + k0 + c4], pack4(t));
}

// ---------------------------------------------------------------------------
extern "C" void kernel_launch(void* const* d_in, const int* in_sizes, int n_in,
                              void* d_out, int out_size, void* d_ws, size_t ws_size,
                              hipStream_t stream)
{
    const float* x_in  = (const float*)d_in[0];
    const float* qkv_w = (const float*)d_in[1];
    const float* qkv_b = (const float*)d_in[2];
    const float* ln_g  = (const float*)d_in[3];
    const float* ln_b  = (const float*)d_in[4];
    const float* fc1_w = (const float*)d_in[5];
    const float* fc1_b = (const float*)d_in[6];
    const float* fc2_w = (const float*)d_in[7];
    const float* fc2_b = (const float*)d_in[8];

    float* xbuf = (float*)d_out;   // fp32 working x (B,N,C) — also final out

    // Workspace carve (bytes). Total ≈ 152.7 MB.
    char* p = (char*)d_ws;
    u16* qkv_wt = (u16*)p; p += (size_t)NLAYERS * 1536 * 512 * 2;
    u16* fc1_wt = (u16*)p; p += (size_t)NLAYERS * 1024 * 512 * 2;
    u16* fc2_wt = (u16*)p; p += (size_t)NLAYERS * 512 * 1024 * 2;
    u16* xb = (u16*)p; p += (size_t)ROWS_TOTAL * CH * 2;
    u16* Qb = (u16*)p; p += (size_t)ROWS_TOTAL * CH * 2;
    u16* Kb = (u16*)p; p += (size_t)ROWS_TOTAL * CH * 2;
    u16* Vt = (u16*)p; p += (size_t)ROWS_TOTAL * CH * 2;
    float* rowsum = (float*)p; p += (size_t)ROWS_TOTAL * 4;
    u16* Sb = (u16*)p;                       // attention phase
    u16* yb = Sb;                            // alias: LN out (MLP phase)
    u16* hb = Sb + (size_t)ROWS_TOTAL * CH;  // alias: GELU out (MLP phase)

    const dim3 blk(256);

    f2bf_kernel<<<dim3(ROWS_TOTAL * CH / 1024), blk, 0, stream>>>(x_in, xb);
    wtrans_kernel<<<dim3(1536 / 32, 512 / 32, NLAYERS), blk, 0, stream>>>(
        qkv_w, qkv_wt, 512, 1536);
    wtrans_kernel<<<dim3(1024 / 32, 512 / 32, NLAYERS), blk, 0, stream>>>(
        fc1_w, fc1_wt, 512, 1024);
    wtrans_kernel<<<dim3(512 / 32, 1024 / 32, NLAYERS), blk, 0, stream>>>(
        fc2_w, fc2_wt, 1024, 512);

    for (int l = 0; l < NLAYERS; ++l) {
        qkv_gemm<<<dim3(128 * 12), blk, 0, stream>>>(
            xb, qkv_wt + (size_t)l * 1536 * 512, qkv_b + (size_t)l * 1536,
            Qb, Kb, Vt, rowsum);
        qk_gemm<<<dim3(2048), blk, 0, stream>>>(Qb, Kb, Sb, rowsum);
        pv_gemm<<<dim3(512), blk, 0, stream>>>(Sb, Vt, rowsum, xbuf);
        ln_kernel<<<dim3(ROWS_TOTAL), blk, 0, stream>>>(
            xbuf, ln_g + (size_t)l * CH, ln_b + (size_t)l * CH, yb);
        fc1_gemm<<<dim3(128 * 8), blk, 0, stream>>>(
            yb, fc1_wt + (size_t)l * 1024 * 512, fc1_b + (size_t)l * 1024, hb);
        if (l < NLAYERS - 1)
            fc2_gemm<false><<<dim3(128 * 4), blk, 0, stream>>>(
                hb, fc2_wt + (size_t)l * 512 * 1024, fc2_b + (size_t)l * 512,
                xbuf, xb);
        else
            fc2_gemm<true><<<dim3(128 * 4), blk, 0, stream>>>(
                hb, fc2_wt + (size_t)l * 512 * 1024, fc2_b + (size_t)l * 512,
                xbuf, xb);
    }
}

// Round 5
// 980.528 us; speedup vs baseline: 1.2083x; 1.0656x over previous
//
#include <hip/hip_runtime.h>
#include <math.h>

typedef unsigned short u16;
typedef __attribute__((ext_vector_type(8))) short bf16x8;
typedef __attribute__((ext_vector_type(4))) float f32x4;
typedef __attribute__((ext_vector_type(4))) unsigned short u16x4;

#define NLAYERS 5
#define BATCH 8
#define SEQ 2048
#define CH 512
#define ROWS_TOTAL (BATCH * SEQ)   // 16384
#define HALF (SEQ / 2)             // 1024
// Q prescale folds softmax scale AND log2(e): qk's epilogue is then a bare
// v_exp_f32 (exp2). 512^-0.5 * 1.4426950408889634 :
#define QSCALE_EXP2 0.06375871529f
// exp cap in exp2 domain (= old 60.0 in e-domain).
#define EXP2_CAP 86.56f

// Double-buffered mm_core staging {As0,Bs0,As1,Bs1} x 16 KB = 64 KB
// -> 2 blocks/CU. Epilogue transpose buffer (32 x 132 fp32) aliases buf0.
#define SMEM_U16 32768
// qk2: single-buffered A(16KB)+B(32KB) = 48KB -> 2 blocks/CU at 512 thr.
#define QK2_U16 24576

// Packed bf16 convert: v_cvt_pk_bf16_f32 (RNE) replaces 3 bit-ops/elem.
__device__ __forceinline__ u16 f2bf(float f) {
    unsigned u = __float_as_uint(f);
    u += 0x7fffu + ((u >> 16) & 1u);   // RNE (scalar fallback)
    return (u16)(u >> 16);
}

__device__ __forceinline__ unsigned pk2(float a, float b) {
    unsigned r;
    asm("v_cvt_pk_bf16_f32 %0, %1, %2" : "=v"(r) : "v"(a), "v"(b));
    return r;
}

__device__ __forceinline__ u16x4 pack4(f32x4 v) {
    union { unsigned u[2]; u16x4 o; } r;
    r.u[0] = pk2(v[0], v[1]);
    r.u[1] = pk2(v[2], v[3]);
    return r.o;
}

__device__ __forceinline__ void st16(u16* p, u16x4 v) { *(u16x4*)p = v; }
__device__ __forceinline__ void st16f(float* p, f32x4 v) { *(f32x4*)p = v; }

__device__ __forceinline__ float fexp2(float x) {
    float r;
    asm("v_exp_f32 %0, %1" : "=v"(r) : "v"(x));
    return r;
}

// 16-byte async global->LDS DMA. LDS dest = wave-uniform base + lane*16.
__device__ __forceinline__ void llds16(const u16* g, u16* l) {
    __builtin_amdgcn_global_load_lds(
        (const __attribute__((address_space(1))) unsigned int*)g,
        (__attribute__((address_space(3))) unsigned int*)l, 16, 0, 0);
}

// XCD-aware decode for M=16384 row-panel GEMMs (qkv/fc1/fc2): XCD k
// (bid&7) owns row-tiles [16k,16k+16) for all col-tiles -> per-XCD L2
// working set = A-panel 2.1 MB + W <= 1.6 MB < 4 MB.
__device__ __forceinline__ void xcd_rc(int& rt, int& ct) {
    const int n = blockIdx.x;
    const int m = n >> 3;
    rt = (n & 7) * 16 + (m & 15);
    ct = m >> 4;
}

// ---------------------------------------------------------------------------
// Core bf16 MFMA GEMM tile: 128x128 C-tile, 256 threads (4 waves, 2x2 of
// 64x64), 16x16x32 MFMA, BK=64 (32 MFMAs per wave per K-step). A[m][k]
// row-major (lda), Bt[n][k] row-major (ldb). LDS unpadded [128][64] u16 per
// matrix; chunk position p holds global chunk p^(row&7) (0 bank conflicts
// measured). 2-deep double buffer, raw s_barrier + counted s_waitcnt
// vmcnt(8): next tile's 8 global_load_lds stay in flight across the barrier.
// ---------------------------------------------------------------------------
__device__ __forceinline__ void mm_issue(const u16* gA, const u16* gB,
                                         u16* lA, u16* lB, int lda, int ldb)
{
#pragma unroll
    for (int i = 0; i < 4; ++i)    // A: 4 issues x (4 waves x 8 rows)
        llds16(gA + (size_t)i * 32 * lda, lA + i * 2048);
#pragma unroll
    for (int i = 0; i < 4; ++i)
        llds16(gB + (size_t)i * 32 * ldb, lB + i * 2048);
}

__device__ __forceinline__ void mm_compute(const u16* As, const u16* Bs,
                                           const int aoff[2][4],
                                           const int boff[2][4],
                                           f32x4 acc[4][4])
{
#pragma unroll
    for (int h = 0; h < 2; ++h) {
        bf16x8 af[4], bfv[4];
#pragma unroll
        for (int t = 0; t < 4; ++t) af[t]  = *(const bf16x8*)&As[aoff[h][t]];
#pragma unroll
        for (int t = 0; t < 4; ++t) bfv[t] = *(const bf16x8*)&Bs[boff[h][t]];
#pragma unroll
        for (int ti = 0; ti < 4; ++ti)
#pragma unroll
            for (int tj = 0; tj < 4; ++tj)
                acc[ti][tj] = __builtin_amdgcn_mfma_f32_16x16x32_bf16(
                    af[ti], bfv[tj], acc[ti][tj], 0, 0, 0);
    }
}

__device__ __forceinline__ void mm_core(
    const u16* __restrict__ A, int lda,
    const u16* __restrict__ Bt, int ldb,
    int row0, int col0, int K,
    u16* SM, f32x4 acc[4][4])
{
    const int tid  = threadIdx.x;
    const int wave = tid >> 6, lane = tid & 63;
    const int wm = (wave & 1) * 64, wn = (wave >> 1) * 64;
    const int q  = lane >> 4,  ln = lane & 15;

    const int sr8 = lane >> 3;
    const int sc  = (lane & 7) ^ sr8;
    const u16* gA = A  + (size_t)(row0 + wave * 8 + sr8) * lda + sc * 8;
    const u16* gB = Bt + (size_t)(col0 + wave * 8 + sr8) * ldb + sc * 8;

    u16* const A0 = SM;
    u16* const B0 = SM + 8192;
    u16* const A1 = SM + 16384;
    u16* const B1 = SM + 24576;
    u16* const w0a = A0 + wave * 512;
    u16* const w0b = B0 + wave * 512;
    u16* const w1a = A1 + wave * 512;
    u16* const w1b = B1 + wave * 512;

    int aoff[2][4], boff[2][4];
#pragma unroll
    for (int h = 0; h < 2; ++h) {
        const int pos = (((h * 4 + q) ^ (ln & 7)) * 8);
#pragma unroll
        for (int t = 0; t < 4; ++t) {
            aoff[h][t] = (wm + t * 16 + ln) * 64 + pos;
            boff[h][t] = (wn + t * 16 + ln) * 64 + pos;
        }
    }

#pragma unroll
    for (int ti = 0; ti < 4; ++ti)
#pragma unroll
        for (int tj = 0; tj < 4; ++tj)
#pragma unroll
            for (int e = 0; e < 4; ++e) acc[ti][tj][e] = 0.f;

    mm_issue(gA, gB, w0a, w0b, lda, ldb);
    gA += 64; gB += 64;

    for (int k0 = 0; k0 < K; k0 += 128) {
        if (k0 + 64 < K) {
            mm_issue(gA, gB, w1a, w1b, lda, ldb);
            gA += 64; gB += 64;
            asm volatile("s_waitcnt vmcnt(8)" ::: "memory");
        } else {
            asm volatile("s_waitcnt vmcnt(0)" ::: "memory");
        }
        __builtin_amdgcn_s_barrier();
        mm_compute(A0, B0, aoff, boff, acc);
        __builtin_amdgcn_s_barrier();
        __builtin_amdgcn_sched_barrier(0);
        if (k0 + 128 < K) {
            mm_issue(gA, gB, w0a, w0b, lda, ldb);
            gA += 64; gB += 64;
            asm volatile("s_waitcnt vmcnt(8)" ::: "memory");
        } else {
            asm volatile("s_waitcnt vmcnt(0)" ::: "memory");
        }
        __builtin_amdgcn_s_barrier();
        mm_compute(A1, B1, aoff, boff, acc);
        __builtin_amdgcn_s_barrier();
        __builtin_amdgcn_sched_barrier(0);
    }
}

// ---------------------------------------------------------------------------
// Epilogue transpose: round-trip acc through LDS so each thread owns a
// contiguous float4 of one row -> vectorized global I/O. FOUR passes of 32
// rows (eb = 32 x 132 fp32 = 16.9 KB; stride 132 == 4 mod 32 -> conflict-
// free). emit(local_row 0..127, col multiple of 4, f32x4).
// ---------------------------------------------------------------------------
template <typename F>
__device__ __forceinline__ void epi_emit(f32x4 acc[4][4], float* eb, F emit)
{
    const int tid = threadIdx.x, wave = tid >> 6, lane = tid & 63;
    const int wn = (wave >> 1) * 64;
    const int q = lane >> 4, ln = lane & 15;
#pragma unroll
    for (int p = 0; p < 4; ++p) {
        __syncthreads();
        if ((wave & 1) == (p >> 1)) {
            const int tibase = (p & 1) * 2;
#pragma unroll
            for (int tj = 0; tj < 4; ++tj)
#pragma unroll
                for (int t2 = 0; t2 < 2; ++t2)
#pragma unroll
                    for (int r = 0; r < 4; ++r)
                        eb[(t2 * 16 + q * 4 + r) * 132 + wn + tj * 16 + ln] =
                            acc[tibase + t2][tj][r];
        }
        __syncthreads();
#pragma unroll
        for (int s = 0; s < 4; ++s) {
            const int row = s * 8 + (tid >> 5);        // 0..31
            const int col = (tid & 31) * 4;
            f32x4 v = *(const f32x4*)&eb[row * 132 + col];
            emit(p * 32 + row, col, v);
        }
    }
}

// ---------------------------------------------------------------------------
// QKV GEMM: A=xb[16384][512], Bt=qkv_wt[1536][512]. 1-D grid (128*12),
// row-panel XCD swizzle. Q (pre-scaled by QSCALE_EXP2) and K use the
// vectorized epi; V region (ct>=8) keeps the direct acc path (transposed
// store Vt[b][c][j]). ct==0 blocks also zero rowsum (replaces the memset
// dispatch; safe: previous layer's pv already consumed rowsum).
// ---------------------------------------------------------------------------
__global__ __launch_bounds__(256) void qkv_gemm(
    const u16* __restrict__ A, const u16* __restrict__ Bt,
    const float* __restrict__ bias,
    u16* __restrict__ Qb, u16* __restrict__ Kb, u16* __restrict__ Vt,
    float* __restrict__ rowsum)
{
    __shared__ __align__(16) u16 SMEM[SMEM_U16];
    f32x4 acc[4][4];
    int rt, ct; xcd_rc(rt, ct);
    const int row0 = rt * 128, col0 = ct * 128;
    if (ct == 0 && threadIdx.x < 128)
        rowsum[row0 + threadIdx.x] = 0.f;
    mm_core(A, CH, Bt, CH, row0, col0, CH, SMEM, acc);

    if (ct < 8) {   // Q or K region (block-uniform)
        u16* dst = (ct < 4) ? Qb : Kb;
        const int cbase = (ct < 4) ? col0 : col0 - CH;
        const float sc = (ct < 4) ? QSCALE_EXP2 : 1.0f;
        epi_emit(acc, (float*)SMEM, [&](int row, int col, f32x4 v) {
            const float4 bb = *(const float4*)&bias[col0 + col];
            v[0] = (v[0] + bb.x) * sc; v[1] = (v[1] + bb.y) * sc;
            v[2] = (v[2] + bb.z) * sc; v[3] = (v[3] + bb.w) * sc;
            st16(&dst[(size_t)(row0 + row) * CH + cbase + col], pack4(v));
        });
    } else {                // V region: direct path, transposed store
        const int tid = threadIdx.x, wave = tid >> 6, lane = tid & 63;
        const int wm = (wave & 1) * 64, wn = (wave >> 1) * 64;
        const int q = lane >> 4, ln = lane & 15;
#pragma unroll
        for (int tj = 0; tj < 4; ++tj) {
            const int gcol = col0 + wn + tj * 16 + ln;
            const float bv = bias[gcol];
#pragma unroll
            for (int ti = 0; ti < 4; ++ti) {
                const int grow = row0 + wm + ti * 16 + q * 4;
                const int b = grow >> 11, j = grow & (SEQ - 1);
                f32x4 vv;
                vv[0] = acc[ti][tj][0] + bv; vv[1] = acc[ti][tj][1] + bv;
                vv[2] = acc[ti][tj][2] + bv; vv[3] = acc[ti][tj][3] + bv;
                st16(&Vt[(size_t)b * CH * SEQ +
                         (size_t)(gcol - 2 * CH) * SEQ + j], pack4(vv));
            }
        }
    }
}

// ---------------------------------------------------------------------------
// QK^T, 2-jt-WIDE: 512 threads / 8 waves, output 128x256 (two adjacent jt
// tiles sharing the staged Q-tile). Single-buffered LDS A 16KB + B 32KB =
// 48KB -> 2 blocks/CU (16 waves/CU). Per K-step: 6 llds16/wave feed 64
// MFMAs/wave over the step pair -> barriers & Q-staging per MFMA halved vs
// the 128x128 core at the SAME co-residency (the axis rounds 0-3 never
// moved). Waves 0-3 = left tile, 4-7 = right; each wave owns 64x64 (acc
// stays 64 VGPR; __launch_bounds__(512,4) holds VGPR<=128 for 4 waves/SIMD).
// Invalid right tile on even diagonals: mask writes zeros to S cols pv
// never reads (Kfull=(it+1)*128). Grid 672 = 84 pair-units x 8 batches.
// ---------------------------------------------------------------------------
__global__ __launch_bounds__(512, 4) void qk2_gemm(
    const u16* __restrict__ Qb, const u16* __restrict__ Kb,
    u16* __restrict__ Sb, float* __restrict__ rowsum)
{
    __shared__ __align__(16) u16 SMEM[QK2_U16];      // 48 KB
    u16* const As = SMEM;                            // [128][64]
    u16* const Bs = SMEM + 8192;                     // [256][64]
    float* const eb = (float*)SMEM;                  // 32 x 260 fp32 = 33.3KB

    const int id = blockIdx.x;
    const int b = id & 7;
    int u = id >> 3, it, pr;                         // u = 0..83
    if (u < 32) { it = u >> 2; pr = u & 3; }
    else {
        int v = u - 32; it = 8; int len = 5;
        while (v >= len) { v -= len; ++it; len = 5 + ((it - 8) >> 1); }
        pr = v;
    }

    const int tid = threadIdx.x;
    const int w = tid >> 6, lane = tid & 63;
    const int wq = w & 3;                    // wave within half
    const int wm = (wq & 1) * 64;
    const int wn = (w >> 2) * 128 + (wq >> 1) * 64;  // col within 256
    const int q = lane >> 4, ln = lane & 15;
    const int sr8 = lane >> 3, sc = (lane & 7) ^ sr8;

    const int row0 = it * 128, col0 = pr * 256;
    const u16* const Qg = Qb + (size_t)b * SEQ * CH;
    const u16* const Kg = Kb + (size_t)b * SEQ * CH;
    u16* const S = Sb + (size_t)b * SEQ * SEQ;

    // staging: wave w owns A rows [16w..16w+16) and B rows [32w..32w+32)
    const u16* gA = Qg + (size_t)(row0 + w * 16 + sr8) * CH + sc * 8;
    const u16* gB = Kg + (size_t)(col0 + w * 32 + sr8) * CH + sc * 8;
    u16* const lA = As + w * 1024;
    u16* const lB = Bs + w * 2048;

    int aoff[2][4], boff[2][4];
#pragma unroll
    for (int h = 0; h < 2; ++h) {
        const int pos = (((h * 4 + q) ^ (ln & 7)) * 8);
#pragma unroll
        for (int t = 0; t < 4; ++t) {
            aoff[h][t] = (wm + t * 16 + ln) * 64 + pos;
            boff[h][t] = (wn + t * 16 + ln) * 64 + pos;
        }
    }

    f32x4 acc[4][4];
#pragma unroll
    for (int ti = 0; ti < 4; ++ti)
#pragma unroll
        for (int tj = 0; tj < 4; ++tj)
#pragma unroll
            for (int e = 0; e < 4; ++e) acc[ti][tj][e] = 0.f;

    for (int s = 0; s < 8; ++s) {
        __syncthreads();               // prev step's frag reads drained
        llds16(gA,               lA);
        llds16(gA +  8 * CH,     lA + 512);
        llds16(gB,               lB);
        llds16(gB +  8 * CH,     lB + 512);
        llds16(gB + 16 * CH,     lB + 1024);
        llds16(gB + 24 * CH,     lB + 1536);
        gA += 64; gB += 64;
        __syncthreads();               // DMA drained -> LDS visible
        mm_compute(As, Bs, aoff, boff, acc);
    }

    // ---- epilogue: 4 passes of 32 rows x 256 cols (eb stride 260) ----
    const bool upper = (it < 8);
#pragma unroll
    for (int p = 0; p < 4; ++p) {
        __syncthreads();
        if ((wq & 1) == (p >> 1)) {
            const int tibase = (p & 1) * 2;
#pragma unroll
            for (int tj = 0; tj < 4; ++tj)
#pragma unroll
                for (int t2 = 0; t2 < 2; ++t2)
#pragma unroll
                    for (int r = 0; r < 4; ++r)
                        eb[(t2 * 16 + q * 4 + r) * 260 + wn + tj * 16 + ln] =
                            acc[tibase + t2][tj][r];
        }
        __syncthreads();
#pragma unroll
        for (int s2 = 0; s2 < 4; ++s2) {
            const int row = s2 * 8 + w;            // 0..31
            const int col = lane * 4;              // 0..252
            f32x4 v = *(const f32x4*)&eb[row * 260 + col];
            const int grow = row0 + p * 32 + row;
            const int gcol = col0 + col;
            f32x4 pv;
#pragma unroll
            for (int e = 0; e < 4; ++e) {
                const bool allowed = upper || (gcol + e <= grow);
                pv[e] = allowed ? fexp2(fminf(v[e], EXP2_CAP)) : 0.f;
            }
            st16(&S[(size_t)grow * SEQ + gcol], pack4(pv));
            float rs = pv[0] + pv[1] + pv[2] + pv[3];
            rs += __shfl_xor(rs, 1, 64);
            rs += __shfl_xor(rs, 2, 64);
            rs += __shfl_xor(rs, 4, 64);
            rs += __shfl_xor(rs, 8, 64);
            rs += __shfl_xor(rs, 16, 64);
            rs += __shfl_xor(rs, 32, 64);
            if (lane == 0)             // one row per wave per s2
                atomicAdd(&rowsum[b * SEQ + grow], rs);
        }
    }
}

// ---------------------------------------------------------------------------
// PV GEMM, full-K per block, normalized output. 1-D grid 512: b=id&7 ->
// XCD=batch (Vt 2MB L2-resident), heavy row-tiles first. Exactly one round.
// ---------------------------------------------------------------------------
__global__ __launch_bounds__(256) void pv_gemm(
    const u16* __restrict__ Sb, const u16* __restrict__ Vt,
    const float* __restrict__ rowsum, float* __restrict__ O)
{
    const int n = blockIdx.x;
    const int b = n & 7, m = n >> 3;        // m = 0..63
    const int it = 15 - (m >> 2), ct = m & 3;
    const int Kfull = ((it < 8) ? 8 : (it + 1)) * 128;
    __shared__ __align__(16) u16 SMEM[SMEM_U16];
    f32x4 acc[4][4];
    const u16* A  = Sb + (size_t)b * SEQ * SEQ;
    const u16* Bt = Vt + (size_t)b * CH * SEQ;
    const int row0 = it * 128, col0 = ct * 128;
    mm_core(A, SEQ, Bt, SEQ, row0, col0, Kfull, SMEM, acc);

    epi_emit(acc, (float*)SMEM, [&](int row, int col, f32x4 v) {
        const int grow = row0 + row;
        const float rden = 1.0f / rowsum[b * SEQ + grow];
        v[0] *= rden; v[1] *= rden; v[2] *= rden; v[3] *= rden;
        st16f(&O[(size_t)(b * SEQ + grow) * CH + col0 + col], v);
    });
}

// ---------------------------------------------------------------------------
// fc1: bf16 in/out, exact GELU epilogue. Row-panel XCD swizzle.
// ---------------------------------------------------------------------------
__global__ __launch_bounds__(256) void fc1_gemm(
    const u16* __restrict__ A, const u16* __restrict__ Bt,
    const float* __restrict__ bias, u16* __restrict__ H)
{
    __shared__ __align__(16) u16 SMEM[SMEM_U16];
    f32x4 acc[4][4];
    int rt, ct; xcd_rc(rt, ct);
    const int row0 = rt * 128, col0 = ct * 128;
    mm_core(A, CH, Bt, CH, row0, col0, CH, SMEM, acc);
    epi_emit(acc, (float*)SMEM, [&](int row, int col, f32x4 v) {
        const float4 bb = *(const float4*)&bias[col0 + col];
        v[0] += bb.x; v[1] += bb.y; v[2] += bb.z; v[3] += bb.w;
#pragma unroll
        for (int e = 0; e < 4; ++e)
            v[e] = 0.5f * v[e] * (1.f + erff(v[e] * 0.70710678118654752f));
        st16(&H[(size_t)(row0 + row) * (2 * CH) + col0 + col], pack4(v));
    });
}

// ---------------------------------------------------------------------------
// fc2: bf16 in, +bias + fp32 residual (normalized O). Writes bf16 Xb always;
// fp32 X only on the final layer. Row-panel XCD swizzle.
// ---------------------------------------------------------------------------
template <bool WRITE_X>
__global__ __launch_bounds__(256) void fc2_gemm(
    const u16* __restrict__ A, const u16* __restrict__ Bt,
    const float* __restrict__ bias, float* __restrict__ X,
    u16* __restrict__ Xb)
{
    __shared__ __align__(16) u16 SMEM[SMEM_U16];
    f32x4 acc[4][4];
    int rt, ct; xcd_rc(rt, ct);
    const int row0 = rt * 128, col0 = ct * 128;
    mm_core(A, 2 * CH, Bt, 2 * CH, row0, col0, 2 * CH, SMEM, acc);
    epi_emit(acc, (float*)SMEM, [&](int row, int col, f32x4 v) {
        const size_t idx = (size_t)(row0 + row) * CH + col0 + col;
        const float4 bb = *(const float4*)&bias[col0 + col];
        const f32x4 xv = *(const f32x4*)&X[idx];
        v[0] += bb.x + xv[0]; v[1] += bb.y + xv[1];
        v[2] += bb.z + xv[2]; v[3] += bb.w + xv[3];
        if (WRITE_X) st16f(&X[idx], v);
        st16(&Xb[idx], pack4(v));
    });
}

// ---------------------------------------------------------------------------
// LayerNorm: fp32 in (normalized attention out), bf16 out (feeds fc1).
// ---------------------------------------------------------------------------
__device__ __forceinline__ float block_sum(float v, volatile float* red, int tid)
{
#pragma unroll
    for (int off = 1; off < 64; off <<= 1) v += __shfl_xor(v, off, 64);
    __syncthreads();
    if ((tid & 63) == 0) red[tid >> 6] = v;
    __syncthreads();
    return red[0] + red[1] + red[2] + red[3];
}

__global__ __launch_bounds__(256) void ln_kernel(
    const float* __restrict__ x, const float* __restrict__ g,
    const float* __restrict__ bta, u16* __restrict__ y)
{
    __shared__ float red[4];
    const int tid = threadIdx.x;
    const size_t base = (size_t)blockIdx.x * CH;
    float x0 = x[base + tid];
    float x1 = x[base + 256 + tid];
    float mu = block_sum(x0 + x1, red, tid) * (1.f / CH);
    float d0 = x0 - mu, d1 = x1 - mu;
    float var = block_sum(d0 * d0 + d1 * d1, red, tid) * (1.f / CH);
    float w = 1.f / sqrtf(var + 1e-5f);
    const float y0 = d0 * w * g[tid]       + bta[tid];
    const float y1 = d1 * w * g[256 + tid] + bta[256 + tid];
    const unsigned pk = pk2(y0, y1);
    y[base + tid]       = (u16)(pk & 0xffffu);
    y[base + 256 + tid] = (u16)(pk >> 16);
}

// ---------------------------------------------------------------------------
// fp32 -> bf16 elementwise (4/thread).
// ---------------------------------------------------------------------------
__global__ __launch_bounds__(256) void f2bf_kernel(
    const float* __restrict__ in, u16* __restrict__ out)
{
    const int i = blockIdx.x * 256 + threadIdx.x;
    float4 vv = ((const float4*)in)[i];
    f32x4 v; v[0] = vv.x; v[1] = vv.y; v[2] = vv.z; v[3] = vv.w;
    u16x4 o = pack4(v);
    *(u16x4*)&out[(size_t)i * 4] = o;
}

// ---------------------------------------------------------------------------
// Weight transpose-convert: in fp32 [L][K][N] -> out bf16 [L][N][K].
// ---------------------------------------------------------------------------
__global__ __launch_bounds__(256) void wtrans_kernel(
    const float* __restrict__ in, u16* __restrict__ out, int K, int N)
{
    __shared__ float tile[32][33];
    const int l = blockIdx.z;
    in  += (size_t)l * K * N;
    out += (size_t)l * K * N;
    const int n0 = blockIdx.x * 32, k0 = blockIdx.y * 32;
    const int r = threadIdx.x >> 3, c4 = (threadIdx.x & 7) * 4;
    float4 v = *(const float4*)&in[(size_t)(k0 + r) * N + n0 + c4];
    tile[r][c4 + 0] = v.x; tile[r][c4 + 1] = v.y;
    tile[r][c4 + 2] = v.z; tile[r][c4 + 3] = v.w;
    __syncthreads();
    f32x4 t;
    t[0] = tile[c4 + 0][r]; t[1] = tile[c4 + 1][r];
    t[2] = tile[c4 + 2][r]; t[3] = tile[c4 + 3][r];
    st16(&out[(size_t)(n0 + r) * K + k0 + c4], pack4(t));
}

// ---------------------------------------------------------------------------
extern "C" void kernel_launch(void* const* d_in, const int* in_sizes, int n_in,
                              void* d_out, int out_size, void* d_ws, size_t ws_size,
                              hipStream_t stream)
{
    const float* x_in  = (const float*)d_in[0];
    const float* qkv_w = (const float*)d_in[1];
    const float* qkv_b = (const float*)d_in[2];
    const float* ln_g  = (const float*)d_in[3];
    const float* ln_b  = (const float*)d_in[4];
    const float* fc1_w = (const float*)d_in[5];
    const float* fc1_b = (const float*)d_in[6];
    const float* fc2_w = (const float*)d_in[7];
    const float* fc2_b = (const float*)d_in[8];

    float* xbuf = (float*)d_out;   // fp32 working x (B,N,C) — also final out

    // Workspace carve (bytes). Total ≈ 152.7 MB.
    char* p = (char*)d_ws;
    u16* qkv_wt = (u16*)p; p += (size_t)NLAYERS * 1536 * 512 * 2;
    u16* fc1_wt = (u16*)p; p += (size_t)NLAYERS * 1024 * 512 * 2;
    u16* fc2_wt = (u16*)p; p += (size_t)NLAYERS * 512 * 1024 * 2;
    u16* xb = (u16*)p; p += (size_t)ROWS_TOTAL * CH * 2;
    u16* Qb = (u16*)p; p += (size_t)ROWS_TOTAL * CH * 2;
    u16* Kb = (u16*)p; p += (size_t)ROWS_TOTAL * CH * 2;
    u16* Vt = (u16*)p; p += (size_t)ROWS_TOTAL * CH * 2;
    float* rowsum = (float*)p; p += (size_t)ROWS_TOTAL * 4;
    u16* Sb = (u16*)p;                       // attention phase
    u16* yb = Sb;                            // alias: LN out (MLP phase)
    u16* hb = Sb + (size_t)ROWS_TOTAL * CH;  // alias: GELU out (MLP phase)

    const dim3 blk(256);
    const dim3 blk2(512);

    f2bf_kernel<<<dim3(ROWS_TOTAL * CH / 1024), blk, 0, stream>>>(x_in, xb);
    wtrans_kernel<<<dim3(1536 / 32, 512 / 32, NLAYERS), blk, 0, stream>>>(
        qkv_w, qkv_wt, 512, 1536);
    wtrans_kernel<<<dim3(1024 / 32, 512 / 32, NLAYERS), blk, 0, stream>>>(
        fc1_w, fc1_wt, 512, 1024);
    wtrans_kernel<<<dim3(512 / 32, 1024 / 32, NLAYERS), blk, 0, stream>>>(
        fc2_w, fc2_wt, 1024, 512);

    for (int l = 0; l < NLAYERS; ++l) {
        qkv_gemm<<<dim3(128 * 12), blk, 0, stream>>>(
            xb, qkv_wt + (size_t)l * 1536 * 512, qkv_b + (size_t)l * 1536,
            Qb, Kb, Vt, rowsum);
        qk2_gemm<<<dim3(672), blk2, 0, stream>>>(Qb, Kb, Sb, rowsum);
        pv_gemm<<<dim3(512), blk, 0, stream>>>(Sb, Vt, rowsum, xbuf);
        ln_kernel<<<dim3(ROWS_TOTAL), blk, 0, stream>>>(
            xbuf, ln_g + (size_t)l * CH, ln_b + (size_t)l * CH, yb);
        fc1_gemm<<<dim3(128 * 8), blk, 0, stream>>>(
            yb, fc1_wt + (size_t)l * 1024 * 512, fc1_b + (size_t)l * 1024, hb);
        if (l < NLAYERS - 1)
            fc2_gemm<false><<<dim3(128 * 4), blk, 0, stream>>>(
                hb, fc2_wt + (size_t)l * 512 * 1024, fc2_b + (size_t)l * 512,
                xbuf, xb);
        else
            fc2_gemm<true><<<dim3(128 * 4), blk, 0, stream>>>(
                hb, fc2_wt + (size_t)l * 512 * 1024, fc2_b + (size_t)l * 512,
                xbuf, xb);
    }
}